// Round 3
// baseline (319.573 us; speedup 1.0000x reference)
//
#include <hip/hip_runtime.h>
#include <math.h>

#define NN 100000
#define NE 1600000
#define IN_DIM 256
#define HD 128           // HEADS*OUT_DIM
#define NEG_SLOPE 0.2f

#define B1SH 9                         // 512 nodes per coarse bucket
#define NPB (1 << B1SH)                // 512
#define NB1 ((NN + NPB - 1) / NPB)     // 196 coarse buckets
#define SC_BLOCKS ((NE / 4 + 1023) / 1024)   // 391 blocks, 4096 edges each
#define DBK 64                         // degree buckets for node sort (clamp 63)

typedef __attribute__((ext_vector_type(8))) __bf16 bf16x8;
typedef __attribute__((ext_vector_type(4))) float floatx4;

__device__ inline unsigned short f2bf(float f) {
    unsigned int b = __float_as_uint(f);
    b += 0x7fffu + ((b >> 16) & 1u);   // round-to-nearest-even
    return (unsigned short)(b >> 16);
}
__device__ inline unsigned int pk(float lo, float hi) {
    return (unsigned int)f2bf(lo) | ((unsigned int)f2bf(hi) << 16);
}
__device__ inline float bflo(unsigned int u) { return __uint_as_float(u << 16); }
__device__ inline float bfhi(unsigned int u) { return __uint_as_float(u & 0xffff0000u); }
__device__ inline float lrelu(float v) { return (v > 0.f) ? v : v * NEG_SLOPE; }

// ---- prep: swizzle W[256][128] fp32 -> bf16 B-fragments for 16x16x32 MFMA ----
__global__ __launch_bounds__(256) void prep_w_kernel(const float* __restrict__ W,
                                                     unsigned int* __restrict__ wswz) {
    int g = blockIdx.x * 256 + threadIdx.x;   // 0..4095
    int lane = g & 63;
    int t = (g >> 6) & 7;
    int c = g >> 9;
    int sub = lane & 15, quad = lane >> 4;
    int n = t * 16 + sub;
    int kbase = c * 32 + quad * 8;
    unsigned int ob = (unsigned int)g * 4;
#pragma unroll
    for (int i = 0; i < 4; ++i) {
        float lo = W[(size_t)(kbase + 2 * i) * HD + n];
        float hi = W[(size_t)(kbase + 2 * i + 1) * HD + n];
        wswz[ob + i] = pk(lo, hi);
    }
}

// ---- GEMM (MFMA, NO LDS): feat_bf16 = bf16(x @ W), el/er fused ----
__global__ __launch_bounds__(256, 4) void gemm_kernel(const float* __restrict__ x,
                                                      const uint4* __restrict__ wswz,
                                                      const float* __restrict__ attn_l,
                                                      const float* __restrict__ attn_r,
                                                      unsigned short* __restrict__ featb,
                                                      float* __restrict__ el,
                                                      float* __restrict__ er) {
    const int tid = threadIdx.x;
    const int lane = tid & 63, wv = tid >> 6;
    const int sub = lane & 15, quad = lane >> 4;
    const int row0 = blockIdx.x * 64 + wv * 16;  // wave covers rows row0..row0+15

    int m = row0 + sub;
    if (m >= NN) m = NN - 1;                     // clamp loads; stores guarded
    const float* xp = x + (size_t)m * IN_DIM + quad * 8;

    bf16x8 af[8];
#pragma unroll
    for (int h = 0; h < 2; ++h) {
        float4 raw[4][2];
#pragma unroll
        for (int c = 0; c < 4; ++c) {
            raw[c][0] = *(const float4*)(xp + (h * 4 + c) * 32);
            raw[c][1] = *(const float4*)(xp + (h * 4 + c) * 32 + 4);
        }
#pragma unroll
        for (int c = 0; c < 4; ++c) {
            uint4 au;
            au.x = pk(raw[c][0].x, raw[c][0].y);
            au.y = pk(raw[c][0].z, raw[c][0].w);
            au.z = pk(raw[c][1].x, raw[c][1].y);
            au.w = pk(raw[c][1].z, raw[c][1].w);
            af[h * 4 + c] = __builtin_bit_cast(bf16x8, au);
        }
    }

    floatx4 acc[8];
#pragma unroll
    for (int t = 0; t < 8; ++t) acc[t] = (floatx4){0.f, 0.f, 0.f, 0.f};

#pragma unroll
    for (int c = 0; c < 8; ++c) {
        uint4 bu[8];
#pragma unroll
        for (int t = 0; t < 8; ++t) bu[t] = wswz[(c * 8 + t) * 64 + lane];
#pragma unroll
        for (int t = 0; t < 8; ++t) {
            bf16x8 bfr = __builtin_bit_cast(bf16x8, bu[t]);
            acc[t] = __builtin_amdgcn_mfma_f32_16x16x32_bf16(af[c], bfr, acc[t], 0, 0, 0);
        }
    }

    float al[8], ar[8];
#pragma unroll
    for (int t = 0; t < 8; ++t) {
        al[t] = attn_l[t * 16 + sub];
        ar[t] = attn_r[t * 16 + sub];
    }

#pragma unroll
    for (int r = 0; r < 4; ++r) {
        int row = row0 + quad * 4 + r;           // C/D: row = quad*4 + reg
        uint4 fv;
        fv.x = pk(acc[0][r], acc[1][r]);
        fv.y = pk(acc[2][r], acc[3][r]);
        fv.z = pk(acc[4][r], acc[5][r]);
        fv.w = pk(acc[6][r], acc[7][r]);
        float pl[4], pr[4];
#pragma unroll
        for (int hh = 0; hh < 4; ++hh) {
            pl[hh] = acc[2 * hh][r] * al[2 * hh] + acc[2 * hh + 1][r] * al[2 * hh + 1];
            pr[hh] = acc[2 * hh][r] * ar[2 * hh] + acc[2 * hh + 1][r] * ar[2 * hh + 1];
        }
#pragma unroll
        for (int o = 1; o < 16; o <<= 1) {
#pragma unroll
            for (int hh = 0; hh < 4; ++hh) {
                pl[hh] += __shfl_xor(pl[hh], o);
                pr[hh] += __shfl_xor(pr[hh], o);
            }
        }
        if (row < NN) {
            *(uint4*)(featb + (size_t)row * HD + sub * 8) = fv;
            if (sub < 4) {
                float vl = (sub == 0) ? pl[0] : (sub == 1) ? pl[1] : (sub == 2) ? pl[2] : pl[3];
                float vr = (sub == 0) ? pr[0] : (sub == 1) ? pr[1] : (sub == 2) ? pr[2] : pr[3];
                el[row * 4 + sub] = vl;
                er[row * 4 + sub] = vr;
            }
        }
    }
}

// ---- precount: per-block LDS histogram over 196 coarse buckets ----
__global__ __launch_bounds__(256) void precount_kernel(const int4* __restrict__ dst4,
                                                       int* __restrict__ gbcnt) {
    __shared__ int cnt[NB1];
    int t = threadIdx.x;
    for (int i = t; i < NB1; i += 256) cnt[i] = 0;
    __syncthreads();
    int base4 = blockIdx.x * 1024;
#pragma unroll
    for (int k = 0; k < 4; ++k) {
        int gi = base4 + k * 256 + t;
        if (gi < NE / 4) {
            int4 d = dst4[gi];
            atomicAdd(&cnt[d.x >> B1SH], 1);
            atomicAdd(&cnt[d.y >> B1SH], 1);
            atomicAdd(&cnt[d.z >> B1SH], 1);
            atomicAdd(&cnt[d.w >> B1SH], 1);
        }
    }
    __syncthreads();
    for (int i = t; i < NB1; i += 256)
        if (cnt[i]) atomicAdd(&gbcnt[i], cnt[i]);
}

// ---- bscan: exclusive scan over 196 bucket counts; init cursors; offs[NN] ----
__global__ __launch_bounds__(256) void bscan_kernel(const int* __restrict__ gbcnt,
                                                    int* __restrict__ regstart,
                                                    int* __restrict__ gcursor,
                                                    int* __restrict__ offs) {
    __shared__ int sh[256];
    int t = threadIdx.x;
    int v = (t < NB1) ? gbcnt[t] : 0;
    sh[t] = v;
    __syncthreads();
    for (int o = 1; o < 256; o <<= 1) {
        int a = (t >= o) ? sh[t - o] : 0;
        __syncthreads();
        sh[t] += a;
        __syncthreads();
    }
    int excl = sh[t] - v;
    if (t < NB1) {
        regstart[t] = excl;
        gcursor[t] = excl;
    }
    if (t == 0) {
        regstart[NB1] = NE;
        offs[NN] = NE;
    }
}

// ---- scatter: bucket edges into packed regions ----
__global__ __launch_bounds__(256) void scatter_kernel(const int4* __restrict__ src4,
                                                      const int4* __restrict__ dst4,
                                                      int* __restrict__ gcursor,
                                                      unsigned int* __restrict__ pkd) {
    __shared__ int cnt[NB1];
    __shared__ int gbase[NB1];
    int t = threadIdx.x;
    for (int i = t; i < NB1; i += 256) cnt[i] = 0;
    __syncthreads();

    int base4 = blockIdx.x * 1024;
    unsigned int pkv[16];
    unsigned int brk[16];
#pragma unroll
    for (int k = 0; k < 4; ++k) {
        int gi = base4 + k * 256 + t;
        bool ok = gi < NE / 4;
        int gic = ok ? gi : 0;
        int4 s = src4[gic];
        int4 d = dst4[gic];
        int dd[4] = {d.x, d.y, d.z, d.w};
        int ss[4] = {s.x, s.y, s.z, s.w};
#pragma unroll
        for (int j4 = 0; j4 < 4; ++j4) {
            int e = k * 4 + j4;
            if (ok) {
                int b = dd[j4] >> B1SH;
                int r = atomicAdd(&cnt[b], 1);                     // local rank
                brk[e] = ((unsigned int)b << 12) | (unsigned int)r; // r < 4096
                pkv[e] = ((unsigned int)(dd[j4] & (NPB - 1)) << 17) | (unsigned int)ss[j4];
            } else {
                brk[e] = 0xFFFFFFFFu;
            }
        }
    }
    __syncthreads();
    for (int i = t; i < NB1; i += 256)
        gbase[i] = cnt[i] ? atomicAdd(&gcursor[i], cnt[i]) : 0;
    __syncthreads();
#pragma unroll
    for (int e = 0; e < 16; ++e) {
        if (brk[e] != 0xFFFFFFFFu) {
            int b = brk[e] >> 12;
            int r = brk[e] & 0xFFF;
            pkd[gbase[b] + r] = pkv[e];
        }
    }
}

// ---- build: fine histogram (= exact degrees), scan -> offs, place csr_src;
//      also accumulates the global degree histogram for node sorting ----
__global__ __launch_bounds__(256) void build_kernel(const unsigned int* __restrict__ pkd,
                                                    const int* __restrict__ regstart,
                                                    int* __restrict__ offs,
                                                    int* __restrict__ csr_src,
                                                    int* __restrict__ dcnt) {
    __shared__ int fcnt[NPB];
    __shared__ int foffs[NPB];
    __shared__ int ssc[256];
    __shared__ int dh[DBK];
    int b = blockIdx.x, t = threadIdx.x;
    int rs = regstart[b], re = regstart[b + 1];
    int n = re - rs;

    for (int i = t; i < NPB; i += 256) fcnt[i] = 0;
    if (t < DBK) dh[t] = 0;
    __syncthreads();
    for (int i = t; i < n; i += 256) {
        unsigned int v = pkd[rs + i];
        atomicAdd(&fcnt[v >> 17], 1);
    }
    __syncthreads();
    int a0 = fcnt[2 * t], a1 = fcnt[2 * t + 1];
    // degree histogram (node sort): fcnt[j] is the exact degree of node b*NPB+j
    {
        int node0 = b * NPB + 2 * t;
        if (node0 < NN)     atomicAdd(&dh[a0 < DBK ? a0 : DBK - 1], 1);
        if (node0 + 1 < NN) atomicAdd(&dh[a1 < DBK ? a1 : DBK - 1], 1);
    }
    int s = a0 + a1;
    ssc[t] = s;
    __syncthreads();
    for (int o = 1; o < 256; o <<= 1) {
        int u = (t >= o) ? ssc[t - o] : 0;
        __syncthreads();
        ssc[t] += u;
        __syncthreads();
    }
    int excl = ssc[t] - s;
    foffs[2 * t] = excl;
    foffs[2 * t + 1] = excl + a0;
    __syncthreads();
    if (t < DBK && dh[t]) atomicAdd(&dcnt[t], dh[t]);
#pragma unroll
    for (int q = 0; q < 2; ++q) {
        int j = t + q * 256;
        int node = b * NPB + j;
        if (node < NN) offs[node] = rs + foffs[j];
    }
    for (int i = t; i < NPB; i += 256) fcnt[i] = 0;   // reuse as cursors
    __syncthreads();
    int i = t;
    for (; i + 768 < n; i += 1024) {
        unsigned int v0 = pkd[rs + i];
        unsigned int v1 = pkd[rs + i + 256];
        unsigned int v2 = pkd[rs + i + 512];
        unsigned int v3 = pkd[rs + i + 768];
        int j0 = v0 >> 17, j1 = v1 >> 17, j2 = v2 >> 17, j3 = v3 >> 17;
        int r0 = atomicAdd(&fcnt[j0], 1);
        int r1 = atomicAdd(&fcnt[j1], 1);
        int r2 = atomicAdd(&fcnt[j2], 1);
        int r3 = atomicAdd(&fcnt[j3], 1);
        csr_src[rs + foffs[j0] + r0] = (int)(v0 & 0x1FFFFu);
        csr_src[rs + foffs[j1] + r1] = (int)(v1 & 0x1FFFFu);
        csr_src[rs + foffs[j2] + r2] = (int)(v2 & 0x1FFFFu);
        csr_src[rs + foffs[j3] + r3] = (int)(v3 & 0x1FFFFu);
    }
    for (; i < n; i += 256) {
        unsigned int v = pkd[rs + i];
        int j = v >> 17;
        int r = atomicAdd(&fcnt[j], 1);
        csr_src[rs + foffs[j] + r] = (int)(v & 0x1FFFFu);
    }
}

// ---- degscan: exclusive scan of the 64 degree-bucket counts (1 wave) ----
__global__ void degscan_kernel(const int* __restrict__ dcnt, int* __restrict__ dcur) {
    int t = threadIdx.x;   // 64 threads
    int v = dcnt[t];
    int s = v;
#pragma unroll
    for (int o = 1; o < 64; o <<= 1) {
        int u = __shfl_up(s, o);
        if (t >= o) s += u;
    }
    dcur[t] = s - v;
}

// ---- permfill: counting-sort nodes by degree (LDS-staged atomics) ----
__global__ __launch_bounds__(256) void permfill_kernel(const int* __restrict__ offs,
                                                       int* __restrict__ dcur,
                                                       int* __restrict__ perm) {
    __shared__ int c[DBK], base[DBK];
    int t = threadIdx.x;
    if (t < DBK) c[t] = 0;
    __syncthreads();
    int n = blockIdx.x * 256 + t;
    int d = 0, r = 0;
    bool ok = n < NN;
    if (ok) {
        d = offs[n + 1] - offs[n];
        if (d > DBK - 1) d = DBK - 1;
        r = atomicAdd(&c[d], 1);
    }
    __syncthreads();
    if (t < DBK) base[t] = c[t] ? atomicAdd(&dcur[t], c[t]) : 0;
    __syncthreads();
    if (ok) perm[base[d] + r] = n;
}

// ---------------- softmax + aggregation (single pass) ----------------
// one wave = 4 nodes (degree-sorted via perm -> near-uniform loop counts);
// 16 lanes per node, lane sub owns cols (d=sub, d=16+sub) of all 4 heads.
// Last chunk is padded to a multiple of 8 with (s=0, w=0) so the gather loop
// is a uniform 8-deep unroll with no tail.
#define CH 32
__global__ __launch_bounds__(256, 4) void aggregate_kernel(const uint4* __restrict__ featu4,
                                                           const float4* __restrict__ el4,
                                                           const float4* __restrict__ er4,
                                                           const int* __restrict__ offs,
                                                           const int* __restrict__ csr_src,
                                                           const int* __restrict__ perm,
                                                           float* __restrict__ out) {
    __shared__ int    s_sv[4][4][CH];
    __shared__ float4 s_a4[4][4][CH];

    const int tid = threadIdx.x;
    const int lane = tid & 63, wv = tid >> 6;
    const int g = lane >> 4, sub = lane & 15;
    const int node = perm[blockIdx.x * 16 + wv * 4 + g];   // NN == 6250*16 exactly
    const int beg = offs[node], end = offs[node + 1];

    const float4 erv = er4[node];
    float4 sm = make_float4(0.f, 0.f, 0.f, 0.f);
    float acc[8];
#pragma unroll
    for (int i = 0; i < 8; ++i) acc[i] = 0.f;

    for (int c0 = beg; c0 < end; c0 += CH) {
        int cnt = end - c0;
        if (cnt > CH) cnt = CH;
        // stage weights: lane handles slots sub and sub+16; pad slots >= cnt
#pragma unroll
        for (int t = 0; t < 2; ++t) {
            int slot = sub + t * 16;
            int sv = 0;
            float4 w = make_float4(0.f, 0.f, 0.f, 0.f);
            if (slot < cnt) {
                sv = csr_src[c0 + slot];
                float4 e = el4[sv];
                w.x = __expf(lrelu(e.x + erv.x));
                w.y = __expf(lrelu(e.y + erv.y));
                w.z = __expf(lrelu(e.z + erv.z));
                w.w = __expf(lrelu(e.w + erv.w));
                sm.x += w.x; sm.y += w.y; sm.z += w.z; sm.w += w.w;
            }
            s_sv[wv][g][slot] = sv;
            s_a4[wv][g][slot] = w;
        }
        // gather: uniform 8-deep unroll (8 dwordx4 loads in flight)
        int rounds = (cnt + 7) >> 3;
        for (int jr = 0; jr < rounds; ++jr) {
            int jb = jr << 3;
            int sv[8];
#pragma unroll
            for (int e = 0; e < 8; ++e) sv[e] = s_sv[wv][g][jb + e];
            uint4 u[8];
#pragma unroll
            for (int e = 0; e < 8; ++e) u[e] = featu4[(size_t)sv[e] * 16 + sub];
            float4 w[8];
#pragma unroll
            for (int e = 0; e < 8; ++e) w[e] = s_a4[wv][g][jb + e];
#pragma unroll
            for (int e = 0; e < 8; ++e) {
                acc[0] = fmaf(w[e].x, bflo(u[e].x), acc[0]);
                acc[1] = fmaf(w[e].x, bfhi(u[e].x), acc[1]);
                acc[2] = fmaf(w[e].y, bflo(u[e].y), acc[2]);
                acc[3] = fmaf(w[e].y, bfhi(u[e].y), acc[3]);
                acc[4] = fmaf(w[e].z, bflo(u[e].z), acc[4]);
                acc[5] = fmaf(w[e].z, bfhi(u[e].z), acc[5]);
                acc[6] = fmaf(w[e].w, bflo(u[e].w), acc[6]);
                acc[7] = fmaf(w[e].w, bfhi(u[e].w), acc[7]);
            }
        }
    }

    // reduce denominators across the 16 lanes of this node
#pragma unroll
    for (int o = 1; o < 16; o <<= 1) {
        sm.x += __shfl_xor(sm.x, o);
        sm.y += __shfl_xor(sm.y, o);
        sm.z += __shfl_xor(sm.z, o);
        sm.w += __shfl_xor(sm.w, o);
    }
    float ix = 1.f / fmaxf(sm.x, 1e-9f);
    float iy = 1.f / fmaxf(sm.y, 1e-9f);
    float iz = 1.f / fmaxf(sm.z, 1e-9f);
    float iw = 1.f / fmaxf(sm.w, 1e-9f);
    float ox = 0.25f * (acc[0] * ix + acc[2] * iy + acc[4] * iz + acc[6] * iw);
    float oy = 0.25f * (acc[1] * ix + acc[3] * iy + acc[5] * iz + acc[7] * iw);
    out[node * 32 + sub]      = ox;
    out[node * 32 + 16 + sub] = oy;
}

// ---------------- launch ----------------
extern "C" void kernel_launch(void* const* d_in, const int* in_sizes, int n_in,
                              void* d_out, int out_size, void* d_ws, size_t ws_size,
                              hipStream_t stream) {
    const float* x      = (const float*)d_in[0];
    const float* W      = (const float*)d_in[1];
    const float* attn_l = (const float*)d_in[2];
    const float* attn_r = (const float*)d_in[3];
    const int*   src    = (const int*)d_in[4];
    const int*   dst    = (const int*)d_in[5];
    float* out = (float*)d_out;

    char* p = (char*)d_ws;
    auto alloc = [&](size_t bytes) -> void* {
        void* r = (void*)p;
        p += (bytes + 255) & ~(size_t)255;
        return r;
    };
    unsigned short* featb = (unsigned short*)alloc((size_t)NN * HD * 2);
    unsigned int*   wswz  = (unsigned int*)alloc(4096 * 16);
    float* el      = (float*)alloc((size_t)NN * 4 * 4);
    float* er      = (float*)alloc((size_t)NN * 4 * 4);
    int*   offs    = (int*)alloc((size_t)(NN + 1) * 4);
    unsigned int* pkd = (unsigned int*)alloc((size_t)NE * 4);
    int*   csr     = (int*)alloc((size_t)NE * 4);
    int*   gbcnt   = (int*)alloc((size_t)NB1 * 4);
    int*   regstart= (int*)alloc((size_t)(NB1 + 1) * 4);
    int*   gcursor = (int*)alloc((size_t)NB1 * 4);
    int*   dcnt    = (int*)alloc((size_t)DBK * 4);
    int*   dcur    = (int*)alloc((size_t)DBK * 4);
    int*   perm    = (int*)alloc((size_t)NN * 4);

    hipMemsetAsync(gbcnt, 0, (size_t)NB1 * 4, stream);
    hipMemsetAsync(dcnt, 0, (size_t)DBK * 4, stream);

    prep_w_kernel<<<16, 256, 0, stream>>>(W, wswz);
    gemm_kernel<<<(NN + 63) / 64, 256, 0, stream>>>(x, (const uint4*)wswz, attn_l, attn_r,
                                                    featb, el, er);
    precount_kernel<<<SC_BLOCKS, 256, 0, stream>>>((const int4*)dst, gbcnt);
    bscan_kernel<<<1, 256, 0, stream>>>(gbcnt, regstart, gcursor, offs);
    scatter_kernel<<<SC_BLOCKS, 256, 0, stream>>>((const int4*)src, (const int4*)dst,
                                                  gcursor, pkd);
    build_kernel<<<NB1, 256, 0, stream>>>(pkd, regstart, offs, csr, dcnt);
    degscan_kernel<<<1, 64, 0, stream>>>(dcnt, dcur);
    permfill_kernel<<<(NN + 255) / 256, 256, 0, stream>>>(offs, dcur, perm);
    aggregate_kernel<<<NN / 16, 256, 0, stream>>>((const uint4*)featb, (const float4*)el,
                                                  (const float4*)er, offs, csr, perm, out);
}

// Round 4
// 302.082 us; speedup vs baseline: 1.0579x; 1.0579x over previous
//
#include <hip/hip_runtime.h>
#include <math.h>

#define NN 100000
#define NE 1600000
#define IN_DIM 256
#define HD 128           // HEADS*OUT_DIM
#define NEG_SLOPE 0.2f

#define B1SH 9                         // 512 nodes per coarse bucket
#define NPB (1 << B1SH)                // 512
#define NB1 ((NN + NPB - 1) / NPB)     // 196 coarse buckets
#define SC_BLOCKS ((NE / 4 + 1023) / 1024)   // 391 blocks, 4096 edges each

typedef __attribute__((ext_vector_type(8))) __bf16 bf16x8;
typedef __attribute__((ext_vector_type(4))) float floatx4;

__device__ inline unsigned short f2bf(float f) {
    unsigned int b = __float_as_uint(f);
    b += 0x7fffu + ((b >> 16) & 1u);   // round-to-nearest-even
    return (unsigned short)(b >> 16);
}
__device__ inline unsigned int pk(float lo, float hi) {
    return (unsigned int)f2bf(lo) | ((unsigned int)f2bf(hi) << 16);
}
__device__ inline float bflo(unsigned int u) { return __uint_as_float(u << 16); }
__device__ inline float bfhi(unsigned int u) { return __uint_as_float(u & 0xffff0000u); }
__device__ inline float lrelu(float v) { return (v > 0.f) ? v : v * NEG_SLOPE; }

// ---- prep: swizzle W[256][128] fp32 -> bf16 B-fragments for 16x16x32 MFMA ----
__global__ __launch_bounds__(256) void prep_w_kernel(const float* __restrict__ W,
                                                     unsigned int* __restrict__ wswz) {
    int g = blockIdx.x * 256 + threadIdx.x;   // 0..4095
    int lane = g & 63;
    int t = (g >> 6) & 7;
    int c = g >> 9;
    int sub = lane & 15, quad = lane >> 4;
    int n = t * 16 + sub;
    int kbase = c * 32 + quad * 8;
    unsigned int ob = (unsigned int)g * 4;
#pragma unroll
    for (int i = 0; i < 4; ++i) {
        float lo = W[(size_t)(kbase + 2 * i) * HD + n];
        float hi = W[(size_t)(kbase + 2 * i + 1) * HD + n];
        wswz[ob + i] = pk(lo, hi);
    }
}

// ---- GEMM (MFMA, NO LDS): feat_bf16 = bf16(x @ W), el/er fused ----
__global__ __launch_bounds__(256) void gemm_kernel(const float* __restrict__ x,
                                                   const uint4* __restrict__ wswz,
                                                   const float* __restrict__ attn_l,
                                                   const float* __restrict__ attn_r,
                                                   unsigned short* __restrict__ featb,
                                                   float* __restrict__ el,
                                                   float* __restrict__ er) {
    const int tid = threadIdx.x;
    const int lane = tid & 63, wv = tid >> 6;
    const int sub = lane & 15, quad = lane >> 4;
    const int row0 = blockIdx.x * 64 + wv * 16;  // wave covers rows row0..row0+15

    int m = row0 + sub;
    if (m >= NN) m = NN - 1;                     // clamp loads; stores guarded
    const float* xp = x + (size_t)m * IN_DIM + quad * 8;

    bf16x8 af[8];
#pragma unroll
    for (int h = 0; h < 2; ++h) {
        float4 raw[4][2];
#pragma unroll
        for (int c = 0; c < 4; ++c) {
            raw[c][0] = *(const float4*)(xp + (h * 4 + c) * 32);
            raw[c][1] = *(const float4*)(xp + (h * 4 + c) * 32 + 4);
        }
#pragma unroll
        for (int c = 0; c < 4; ++c) {
            uint4 au;
            au.x = pk(raw[c][0].x, raw[c][0].y);
            au.y = pk(raw[c][0].z, raw[c][0].w);
            au.z = pk(raw[c][1].x, raw[c][1].y);
            au.w = pk(raw[c][1].z, raw[c][1].w);
            af[h * 4 + c] = __builtin_bit_cast(bf16x8, au);
        }
    }

    floatx4 acc[8];
#pragma unroll
    for (int t = 0; t < 8; ++t) acc[t] = (floatx4){0.f, 0.f, 0.f, 0.f};

#pragma unroll
    for (int c = 0; c < 8; ++c) {
        uint4 bu[8];
#pragma unroll
        for (int t = 0; t < 8; ++t) bu[t] = wswz[(c * 8 + t) * 64 + lane];
#pragma unroll
        for (int t = 0; t < 8; ++t) {
            bf16x8 bfr = __builtin_bit_cast(bf16x8, bu[t]);
            acc[t] = __builtin_amdgcn_mfma_f32_16x16x32_bf16(af[c], bfr, acc[t], 0, 0, 0);
        }
    }

    float al[8], ar[8];
#pragma unroll
    for (int t = 0; t < 8; ++t) {
        al[t] = attn_l[t * 16 + sub];
        ar[t] = attn_r[t * 16 + sub];
    }

#pragma unroll
    for (int r = 0; r < 4; ++r) {
        int row = row0 + quad * 4 + r;           // C/D: row = quad*4 + reg
        uint4 fv;
        fv.x = pk(acc[0][r], acc[1][r]);
        fv.y = pk(acc[2][r], acc[3][r]);
        fv.z = pk(acc[4][r], acc[5][r]);
        fv.w = pk(acc[6][r], acc[7][r]);
        float pl[4], pr[4];
#pragma unroll
        for (int hh = 0; hh < 4; ++hh) {
            pl[hh] = acc[2 * hh][r] * al[2 * hh] + acc[2 * hh + 1][r] * al[2 * hh + 1];
            pr[hh] = acc[2 * hh][r] * ar[2 * hh] + acc[2 * hh + 1][r] * ar[2 * hh + 1];
        }
#pragma unroll
        for (int o = 1; o < 16; o <<= 1) {
#pragma unroll
            for (int hh = 0; hh < 4; ++hh) {
                pl[hh] += __shfl_xor(pl[hh], o);
                pr[hh] += __shfl_xor(pr[hh], o);
            }
        }
        if (row < NN) {
            *(uint4*)(featb + (size_t)row * HD + sub * 8) = fv;
            if (sub < 4) {
                float vl = (sub == 0) ? pl[0] : (sub == 1) ? pl[1] : (sub == 2) ? pl[2] : pl[3];
                float vr = (sub == 0) ? pr[0] : (sub == 1) ? pr[1] : (sub == 2) ? pr[2] : pr[3];
                el[row * 4 + sub] = vl;
                er[row * 4 + sub] = vr;
            }
        }
    }
}

// ---- precount: per-block LDS histogram over 196 coarse buckets ----
__global__ __launch_bounds__(256) void precount_kernel(const int4* __restrict__ dst4,
                                                       int* __restrict__ gbcnt) {
    __shared__ int cnt[NB1];
    int t = threadIdx.x;
    for (int i = t; i < NB1; i += 256) cnt[i] = 0;
    __syncthreads();
    int base4 = blockIdx.x * 1024;
#pragma unroll
    for (int k = 0; k < 4; ++k) {
        int gi = base4 + k * 256 + t;
        if (gi < NE / 4) {
            int4 d = dst4[gi];
            atomicAdd(&cnt[d.x >> B1SH], 1);
            atomicAdd(&cnt[d.y >> B1SH], 1);
            atomicAdd(&cnt[d.z >> B1SH], 1);
            atomicAdd(&cnt[d.w >> B1SH], 1);
        }
    }
    __syncthreads();
    for (int i = t; i < NB1; i += 256)
        if (cnt[i]) atomicAdd(&gbcnt[i], cnt[i]);
}

// ---- bscan: exclusive scan over 196 bucket counts; init cursors; offs[NN] ----
__global__ __launch_bounds__(256) void bscan_kernel(const int* __restrict__ gbcnt,
                                                    int* __restrict__ regstart,
                                                    int* __restrict__ gcursor,
                                                    int* __restrict__ offs) {
    __shared__ int sh[256];
    int t = threadIdx.x;
    int v = (t < NB1) ? gbcnt[t] : 0;
    sh[t] = v;
    __syncthreads();
    for (int o = 1; o < 256; o <<= 1) {
        int a = (t >= o) ? sh[t - o] : 0;
        __syncthreads();
        sh[t] += a;
        __syncthreads();
    }
    int excl = sh[t] - v;
    if (t < NB1) {
        regstart[t] = excl;
        gcursor[t] = excl;
    }
    if (t == 0) {
        regstart[NB1] = NE;
        offs[NN] = NE;
    }
}

// ---- scatter: bucket edges into packed regions ----
__global__ __launch_bounds__(256) void scatter_kernel(const int4* __restrict__ src4,
                                                      const int4* __restrict__ dst4,
                                                      int* __restrict__ gcursor,
                                                      unsigned int* __restrict__ pkd) {
    __shared__ int cnt[NB1];
    __shared__ int gbase[NB1];
    int t = threadIdx.x;
    for (int i = t; i < NB1; i += 256) cnt[i] = 0;
    __syncthreads();

    int base4 = blockIdx.x * 1024;
    unsigned int pkv[16];
    unsigned int brk[16];
#pragma unroll
    for (int k = 0; k < 4; ++k) {
        int gi = base4 + k * 256 + t;
        bool ok = gi < NE / 4;
        int gic = ok ? gi : 0;
        int4 s = src4[gic];
        int4 d = dst4[gic];
        int dd[4] = {d.x, d.y, d.z, d.w};
        int ss[4] = {s.x, s.y, s.z, s.w};
#pragma unroll
        for (int j4 = 0; j4 < 4; ++j4) {
            int e = k * 4 + j4;
            if (ok) {
                int b = dd[j4] >> B1SH;
                int r = atomicAdd(&cnt[b], 1);                     // local rank
                brk[e] = ((unsigned int)b << 12) | (unsigned int)r; // r < 4096
                pkv[e] = ((unsigned int)(dd[j4] & (NPB - 1)) << 17) | (unsigned int)ss[j4];
            } else {
                brk[e] = 0xFFFFFFFFu;
            }
        }
    }
    __syncthreads();
    for (int i = t; i < NB1; i += 256)
        gbase[i] = cnt[i] ? atomicAdd(&gcursor[i], cnt[i]) : 0;
    __syncthreads();
#pragma unroll
    for (int e = 0; e < 16; ++e) {
        if (brk[e] != 0xFFFFFFFFu) {
            int b = brk[e] >> 12;
            int r = brk[e] & 0xFFF;
            pkd[gbase[b] + r] = pkv[e];
        }
    }
}

// ---- build: fine histogram (= exact degrees), scan -> offs, place csr_src ----
__global__ __launch_bounds__(256) void build_kernel(const unsigned int* __restrict__ pkd,
                                                    const int* __restrict__ regstart,
                                                    int* __restrict__ offs,
                                                    int* __restrict__ csr_src) {
    __shared__ int fcnt[NPB];
    __shared__ int foffs[NPB];
    __shared__ int ssc[256];
    int b = blockIdx.x, t = threadIdx.x;
    int rs = regstart[b], re = regstart[b + 1];
    int n = re - rs;

    for (int i = t; i < NPB; i += 256) fcnt[i] = 0;
    __syncthreads();
    for (int i = t; i < n; i += 256) {
        unsigned int v = pkd[rs + i];
        atomicAdd(&fcnt[v >> 17], 1);
    }
    __syncthreads();
    int a0 = fcnt[2 * t], a1 = fcnt[2 * t + 1];
    int s = a0 + a1;
    ssc[t] = s;
    __syncthreads();
    for (int o = 1; o < 256; o <<= 1) {
        int u = (t >= o) ? ssc[t - o] : 0;
        __syncthreads();
        ssc[t] += u;
        __syncthreads();
    }
    int excl = ssc[t] - s;
    foffs[2 * t] = excl;
    foffs[2 * t + 1] = excl + a0;
    __syncthreads();
#pragma unroll
    for (int q = 0; q < 2; ++q) {
        int j = t + q * 256;
        int node = b * NPB + j;
        if (node < NN) offs[node] = rs + foffs[j];
    }
    for (int i = t; i < NPB; i += 256) fcnt[i] = 0;   // reuse as cursors
    __syncthreads();
    int i = t;
    for (; i + 768 < n; i += 1024) {
        unsigned int v0 = pkd[rs + i];
        unsigned int v1 = pkd[rs + i + 256];
        unsigned int v2 = pkd[rs + i + 512];
        unsigned int v3 = pkd[rs + i + 768];
        int j0 = v0 >> 17, j1 = v1 >> 17, j2 = v2 >> 17, j3 = v3 >> 17;
        int r0 = atomicAdd(&fcnt[j0], 1);
        int r1 = atomicAdd(&fcnt[j1], 1);
        int r2 = atomicAdd(&fcnt[j2], 1);
        int r3 = atomicAdd(&fcnt[j3], 1);
        csr_src[rs + foffs[j0] + r0] = (int)(v0 & 0x1FFFFu);
        csr_src[rs + foffs[j1] + r1] = (int)(v1 & 0x1FFFFu);
        csr_src[rs + foffs[j2] + r2] = (int)(v2 & 0x1FFFFu);
        csr_src[rs + foffs[j3] + r3] = (int)(v3 & 0x1FFFFu);
    }
    for (; i < n; i += 256) {
        unsigned int v = pkd[rs + i];
        int j = v >> 17;
        int r = atomicAdd(&fcnt[j], 1);
        csr_src[rs + foffs[j] + r] = (int)(v & 0x1FFFFu);
    }
}

// ---------------- softmax + aggregation (single pass) ----------------
// one wave = 4 nodes; 16 lanes per node. Block handles its original
// contiguous 16-node window, but nodes are rank-sorted by degree in LDS and
// dealt to waves in sorted order -> each wave's 4 nodes have near-equal
// degree (divergence fix with zero global traffic / locality cost).
// LDS staging arrays padded (+1 slot) so the 4 groups' broadcast reads hit
// different banks. Gather is a uniform 8-deep unroll (8 loads in flight).
#define CH 32
__global__ __launch_bounds__(256) void aggregate_kernel(const uint4* __restrict__ featu4,
                                                        const float4* __restrict__ el4,
                                                        const float4* __restrict__ er4,
                                                        const int* __restrict__ offs,
                                                        const int* __restrict__ csr_src,
                                                        float* __restrict__ out) {
    __shared__ int    s_sv[4][4][CH + 1];
    __shared__ float4 s_a4[4][4][CH + 1];
    __shared__ int sdeg[16], smap[16];

    const int tid = threadIdx.x;
    const int lane = tid & 63, wv = tid >> 6;
    const int g = lane >> 4, sub = lane & 15;

    // within-block degree sort of the 16 nodes (O(16^2) rank compare)
    if (tid < 16) {
        int n0 = blockIdx.x * 16 + tid;            // NN == 6250*16 exactly
        sdeg[tid] = offs[n0 + 1] - offs[n0];
    }
    __syncthreads();
    if (tid < 16) {
        int d = sdeg[tid];
        int rank = 0;
#pragma unroll
        for (int j = 0; j < 16; ++j) {
            int dj = sdeg[j];
            rank += (dj < d) || (dj == d && j < tid);
        }
        smap[rank] = blockIdx.x * 16 + tid;
    }
    __syncthreads();
    const int node = smap[wv * 4 + g];
    const int beg = offs[node], end = offs[node + 1];

    const float4 erv = er4[node];
    float4 sm = make_float4(0.f, 0.f, 0.f, 0.f);
    float acc[8];
#pragma unroll
    for (int i = 0; i < 8; ++i) acc[i] = 0.f;

    for (int c0 = beg; c0 < end; c0 += CH) {
        int cnt = end - c0;
        if (cnt > CH) cnt = CH;
        // stage weights: lane handles slots sub and sub+16; pad slots >= cnt
#pragma unroll
        for (int t = 0; t < 2; ++t) {
            int slot = sub + t * 16;
            int sv = 0;
            float4 w = make_float4(0.f, 0.f, 0.f, 0.f);
            if (slot < cnt) {
                sv = csr_src[c0 + slot];
                float4 e = el4[sv];
                w.x = __expf(lrelu(e.x + erv.x));
                w.y = __expf(lrelu(e.y + erv.y));
                w.z = __expf(lrelu(e.z + erv.z));
                w.w = __expf(lrelu(e.w + erv.w));
                sm.x += w.x; sm.y += w.y; sm.z += w.z; sm.w += w.w;
            }
            s_sv[wv][g][slot] = sv;
            s_a4[wv][g][slot] = w;
        }
        // gather: uniform 8-deep unroll (8 dwordx4 loads in flight)
        int rounds = (cnt + 7) >> 3;
        for (int jr = 0; jr < rounds; ++jr) {
            int jb = jr << 3;
            int sv[8];
#pragma unroll
            for (int e = 0; e < 8; ++e) sv[e] = s_sv[wv][g][jb + e];
            uint4 u[8];
#pragma unroll
            for (int e = 0; e < 8; ++e) u[e] = featu4[(size_t)sv[e] * 16 + sub];
            float4 w[8];
#pragma unroll
            for (int e = 0; e < 8; ++e) w[e] = s_a4[wv][g][jb + e];
#pragma unroll
            for (int e = 0; e < 8; ++e) {
                acc[0] = fmaf(w[e].x, bflo(u[e].x), acc[0]);
                acc[1] = fmaf(w[e].x, bfhi(u[e].x), acc[1]);
                acc[2] = fmaf(w[e].y, bflo(u[e].y), acc[2]);
                acc[3] = fmaf(w[e].y, bfhi(u[e].y), acc[3]);
                acc[4] = fmaf(w[e].z, bflo(u[e].z), acc[4]);
                acc[5] = fmaf(w[e].z, bfhi(u[e].z), acc[5]);
                acc[6] = fmaf(w[e].w, bflo(u[e].w), acc[6]);
                acc[7] = fmaf(w[e].w, bfhi(u[e].w), acc[7]);
            }
        }
    }

    // reduce denominators across the 16 lanes of this node
#pragma unroll
    for (int o = 1; o < 16; o <<= 1) {
        sm.x += __shfl_xor(sm.x, o);
        sm.y += __shfl_xor(sm.y, o);
        sm.z += __shfl_xor(sm.z, o);
        sm.w += __shfl_xor(sm.w, o);
    }
    float ix = 1.f / fmaxf(sm.x, 1e-9f);
    float iy = 1.f / fmaxf(sm.y, 1e-9f);
    float iz = 1.f / fmaxf(sm.z, 1e-9f);
    float iw = 1.f / fmaxf(sm.w, 1e-9f);
    float ox = 0.25f * (acc[0] * ix + acc[2] * iy + acc[4] * iz + acc[6] * iw);
    float oy = 0.25f * (acc[1] * ix + acc[3] * iy + acc[5] * iz + acc[7] * iw);
    out[node * 32 + sub]      = ox;
    out[node * 32 + 16 + sub] = oy;
}

// ---------------- launch ----------------
extern "C" void kernel_launch(void* const* d_in, const int* in_sizes, int n_in,
                              void* d_out, int out_size, void* d_ws, size_t ws_size,
                              hipStream_t stream) {
    const float* x      = (const float*)d_in[0];
    const float* W      = (const float*)d_in[1];
    const float* attn_l = (const float*)d_in[2];
    const float* attn_r = (const float*)d_in[3];
    const int*   src    = (const int*)d_in[4];
    const int*   dst    = (const int*)d_in[5];
    float* out = (float*)d_out;

    char* p = (char*)d_ws;
    auto alloc = [&](size_t bytes) -> void* {
        void* r = (void*)p;
        p += (bytes + 255) & ~(size_t)255;
        return r;
    };
    unsigned short* featb = (unsigned short*)alloc((size_t)NN * HD * 2);
    unsigned int*   wswz  = (unsigned int*)alloc(4096 * 16);
    float* el      = (float*)alloc((size_t)NN * 4 * 4);
    float* er      = (float*)alloc((size_t)NN * 4 * 4);
    int*   offs    = (int*)alloc((size_t)(NN + 1) * 4);
    unsigned int* pkd = (unsigned int*)alloc((size_t)NE * 4);
    int*   csr     = (int*)alloc((size_t)NE * 4);
    int*   gbcnt   = (int*)alloc((size_t)NB1 * 4);
    int*   regstart= (int*)alloc((size_t)(NB1 + 1) * 4);
    int*   gcursor = (int*)alloc((size_t)NB1 * 4);

    hipMemsetAsync(gbcnt, 0, (size_t)NB1 * 4, stream);

    prep_w_kernel<<<16, 256, 0, stream>>>(W, wswz);
    gemm_kernel<<<(NN + 63) / 64, 256, 0, stream>>>(x, (const uint4*)wswz, attn_l, attn_r,
                                                    featb, el, er);
    precount_kernel<<<SC_BLOCKS, 256, 0, stream>>>((const int4*)dst, gbcnt);
    bscan_kernel<<<1, 256, 0, stream>>>(gbcnt, regstart, gcursor, offs);
    scatter_kernel<<<SC_BLOCKS, 256, 0, stream>>>((const int4*)src, (const int4*)dst,
                                                  gcursor, pkd);
    build_kernel<<<NB1, 256, 0, stream>>>(pkd, regstart, offs, csr);
    aggregate_kernel<<<NN / 16, 256, 0, stream>>>((const uint4*)featb, (const float4*)el,
                                                  (const float4*)er, offs, csr, out);
}

// Round 5
// 301.495 us; speedup vs baseline: 1.0600x; 1.0019x over previous
//
#include <hip/hip_runtime.h>
#include <math.h>

#define NN 100000
#define NE 1600000
#define IN_DIM 256
#define HD 128           // HEADS*OUT_DIM
#define NEG_SLOPE 0.2f

#define B1SH 9                         // 512 nodes per coarse bucket
#define NPB (1 << B1SH)                // 512
#define NB1 ((NN + NPB - 1) / NPB)     // 196 coarse buckets
#define SC_BLOCKS ((NE / 4 + 1023) / 1024)   // 391 blocks, 4096 edges each

typedef __attribute__((ext_vector_type(8))) __bf16 bf16x8;
typedef __attribute__((ext_vector_type(4))) float floatx4;
typedef __attribute__((ext_vector_type(2))) float f32x2;

__device__ inline unsigned short f2bf(float f) {
    unsigned int b = __float_as_uint(f);
    b += 0x7fffu + ((b >> 16) & 1u);   // round-to-nearest-even
    return (unsigned short)(b >> 16);
}
__device__ inline unsigned int pk(float lo, float hi) {
    return (unsigned int)f2bf(lo) | ((unsigned int)f2bf(hi) << 16);
}
__device__ inline float lrelu(float v) { return (v > 0.f) ? v : v * NEG_SLOPE; }
__device__ inline f32x2 un2(unsigned int v) {
    f32x2 r;
    r.x = __uint_as_float(v << 16);
    r.y = __uint_as_float(v & 0xffff0000u);
    return r;
}

// ---- prep: swizzle W[256][128] fp32 -> bf16 B-fragments for 16x16x32 MFMA ----
__global__ __launch_bounds__(256) void prep_w_kernel(const float* __restrict__ W,
                                                     unsigned int* __restrict__ wswz) {
    int g = blockIdx.x * 256 + threadIdx.x;   // 0..4095
    int lane = g & 63;
    int t = (g >> 6) & 7;
    int c = g >> 9;
    int sub = lane & 15, quad = lane >> 4;
    int n = t * 16 + sub;
    int kbase = c * 32 + quad * 8;
    unsigned int ob = (unsigned int)g * 4;
#pragma unroll
    for (int i = 0; i < 4; ++i) {
        float lo = W[(size_t)(kbase + 2 * i) * HD + n];
        float hi = W[(size_t)(kbase + 2 * i + 1) * HD + n];
        wswz[ob + i] = pk(lo, hi);
    }
}

// ---- GEMM (MFMA, NO LDS): feat_bf16 = bf16(x @ W), el/er fused ----
__global__ __launch_bounds__(256) void gemm_kernel(const float* __restrict__ x,
                                                   const uint4* __restrict__ wswz,
                                                   const float* __restrict__ attn_l,
                                                   const float* __restrict__ attn_r,
                                                   unsigned short* __restrict__ featb,
                                                   float* __restrict__ el,
                                                   float* __restrict__ er) {
    const int tid = threadIdx.x;
    const int lane = tid & 63, wv = tid >> 6;
    const int sub = lane & 15, quad = lane >> 4;
    const int row0 = blockIdx.x * 64 + wv * 16;  // wave covers rows row0..row0+15

    int m = row0 + sub;
    if (m >= NN) m = NN - 1;                     // clamp loads; stores guarded
    const float* xp = x + (size_t)m * IN_DIM + quad * 8;

    bf16x8 af[8];
#pragma unroll
    for (int h = 0; h < 2; ++h) {
        float4 raw[4][2];
#pragma unroll
        for (int c = 0; c < 4; ++c) {
            raw[c][0] = *(const float4*)(xp + (h * 4 + c) * 32);
            raw[c][1] = *(const float4*)(xp + (h * 4 + c) * 32 + 4);
        }
#pragma unroll
        for (int c = 0; c < 4; ++c) {
            uint4 au;
            au.x = pk(raw[c][0].x, raw[c][0].y);
            au.y = pk(raw[c][0].z, raw[c][0].w);
            au.z = pk(raw[c][1].x, raw[c][1].y);
            au.w = pk(raw[c][1].z, raw[c][1].w);
            af[h * 4 + c] = __builtin_bit_cast(bf16x8, au);
        }
    }

    floatx4 acc[8];
#pragma unroll
    for (int t = 0; t < 8; ++t) acc[t] = (floatx4){0.f, 0.f, 0.f, 0.f};

#pragma unroll
    for (int c = 0; c < 8; ++c) {
        uint4 bu[8];
#pragma unroll
        for (int t = 0; t < 8; ++t) bu[t] = wswz[(c * 8 + t) * 64 + lane];
#pragma unroll
        for (int t = 0; t < 8; ++t) {
            bf16x8 bfr = __builtin_bit_cast(bf16x8, bu[t]);
            acc[t] = __builtin_amdgcn_mfma_f32_16x16x32_bf16(af[c], bfr, acc[t], 0, 0, 0);
        }
    }

    float al[8], ar[8];
#pragma unroll
    for (int t = 0; t < 8; ++t) {
        al[t] = attn_l[t * 16 + sub];
        ar[t] = attn_r[t * 16 + sub];
    }

#pragma unroll
    for (int r = 0; r < 4; ++r) {
        int row = row0 + quad * 4 + r;           // C/D: row = quad*4 + reg
        uint4 fv;
        fv.x = pk(acc[0][r], acc[1][r]);
        fv.y = pk(acc[2][r], acc[3][r]);
        fv.z = pk(acc[4][r], acc[5][r]);
        fv.w = pk(acc[6][r], acc[7][r]);
        float pl[4], pr[4];
#pragma unroll
        for (int hh = 0; hh < 4; ++hh) {
            pl[hh] = acc[2 * hh][r] * al[2 * hh] + acc[2 * hh + 1][r] * al[2 * hh + 1];
            pr[hh] = acc[2 * hh][r] * ar[2 * hh] + acc[2 * hh + 1][r] * ar[2 * hh + 1];
        }
#pragma unroll
        for (int o = 1; o < 16; o <<= 1) {
#pragma unroll
            for (int hh = 0; hh < 4; ++hh) {
                pl[hh] += __shfl_xor(pl[hh], o);
                pr[hh] += __shfl_xor(pr[hh], o);
            }
        }
        if (row < NN) {
            *(uint4*)(featb + (size_t)row * HD + sub * 8) = fv;
            if (sub < 4) {
                float vl = (sub == 0) ? pl[0] : (sub == 1) ? pl[1] : (sub == 2) ? pl[2] : pl[3];
                float vr = (sub == 0) ? pr[0] : (sub == 1) ? pr[1] : (sub == 2) ? pr[2] : pr[3];
                el[row * 4 + sub] = vl;
                er[row * 4 + sub] = vr;
            }
        }
    }
}

// ---- precount: per-block LDS histogram over 196 coarse buckets ----
__global__ __launch_bounds__(256) void precount_kernel(const int4* __restrict__ dst4,
                                                       int* __restrict__ gbcnt) {
    __shared__ int cnt[NB1];
    int t = threadIdx.x;
    for (int i = t; i < NB1; i += 256) cnt[i] = 0;
    __syncthreads();
    int base4 = blockIdx.x * 1024;
#pragma unroll
    for (int k = 0; k < 4; ++k) {
        int gi = base4 + k * 256 + t;
        if (gi < NE / 4) {
            int4 d = dst4[gi];
            atomicAdd(&cnt[d.x >> B1SH], 1);
            atomicAdd(&cnt[d.y >> B1SH], 1);
            atomicAdd(&cnt[d.z >> B1SH], 1);
            atomicAdd(&cnt[d.w >> B1SH], 1);
        }
    }
    __syncthreads();
    for (int i = t; i < NB1; i += 256)
        if (cnt[i]) atomicAdd(&gbcnt[i], cnt[i]);
}

// ---- bscan: exclusive scan over 196 bucket counts; init cursors; offs[NN] ----
__global__ __launch_bounds__(256) void bscan_kernel(const int* __restrict__ gbcnt,
                                                    int* __restrict__ regstart,
                                                    int* __restrict__ gcursor,
                                                    int* __restrict__ offs) {
    __shared__ int sh[256];
    int t = threadIdx.x;
    int v = (t < NB1) ? gbcnt[t] : 0;
    sh[t] = v;
    __syncthreads();
    for (int o = 1; o < 256; o <<= 1) {
        int a = (t >= o) ? sh[t - o] : 0;
        __syncthreads();
        sh[t] += a;
        __syncthreads();
    }
    int excl = sh[t] - v;
    if (t < NB1) {
        regstart[t] = excl;
        gcursor[t] = excl;
    }
    if (t == 0) {
        regstart[NB1] = NE;
        offs[NN] = NE;
    }
}

// ---- scatter: bucket edges into packed regions ----
__global__ __launch_bounds__(256) void scatter_kernel(const int4* __restrict__ src4,
                                                      const int4* __restrict__ dst4,
                                                      int* __restrict__ gcursor,
                                                      unsigned int* __restrict__ pkd) {
    __shared__ int cnt[NB1];
    __shared__ int gbase[NB1];
    int t = threadIdx.x;
    for (int i = t; i < NB1; i += 256) cnt[i] = 0;
    __syncthreads();

    int base4 = blockIdx.x * 1024;
    unsigned int pkv[16];
    unsigned int brk[16];
#pragma unroll
    for (int k = 0; k < 4; ++k) {
        int gi = base4 + k * 256 + t;
        bool ok = gi < NE / 4;
        int gic = ok ? gi : 0;
        int4 s = src4[gic];
        int4 d = dst4[gic];
        int dd[4] = {d.x, d.y, d.z, d.w};
        int ss[4] = {s.x, s.y, s.z, s.w};
#pragma unroll
        for (int j4 = 0; j4 < 4; ++j4) {
            int e = k * 4 + j4;
            if (ok) {
                int b = dd[j4] >> B1SH;
                int r = atomicAdd(&cnt[b], 1);                     // local rank
                brk[e] = ((unsigned int)b << 12) | (unsigned int)r; // r < 4096
                pkv[e] = ((unsigned int)(dd[j4] & (NPB - 1)) << 17) | (unsigned int)ss[j4];
            } else {
                brk[e] = 0xFFFFFFFFu;
            }
        }
    }
    __syncthreads();
    for (int i = t; i < NB1; i += 256)
        gbase[i] = cnt[i] ? atomicAdd(&gcursor[i], cnt[i]) : 0;
    __syncthreads();
#pragma unroll
    for (int e = 0; e < 16; ++e) {
        if (brk[e] != 0xFFFFFFFFu) {
            int b = brk[e] >> 12;
            int r = brk[e] & 0xFFF;
            pkd[gbase[b] + r] = pkv[e];
        }
    }
}

// ---- build: fine histogram (= exact degrees), scan -> offs, place csr_src ----
__global__ __launch_bounds__(256) void build_kernel(const unsigned int* __restrict__ pkd,
                                                    const int* __restrict__ regstart,
                                                    int* __restrict__ offs,
                                                    int* __restrict__ csr_src) {
    __shared__ int fcnt[NPB];
    __shared__ int foffs[NPB];
    __shared__ int ssc[256];
    int b = blockIdx.x, t = threadIdx.x;
    int rs = regstart[b], re = regstart[b + 1];
    int n = re - rs;

    for (int i = t; i < NPB; i += 256) fcnt[i] = 0;
    __syncthreads();
    for (int i = t; i < n; i += 256) {
        unsigned int v = pkd[rs + i];
        atomicAdd(&fcnt[v >> 17], 1);
    }
    __syncthreads();
    int a0 = fcnt[2 * t], a1 = fcnt[2 * t + 1];
    int s = a0 + a1;
    ssc[t] = s;
    __syncthreads();
    for (int o = 1; o < 256; o <<= 1) {
        int u = (t >= o) ? ssc[t - o] : 0;
        __syncthreads();
        ssc[t] += u;
        __syncthreads();
    }
    int excl = ssc[t] - s;
    foffs[2 * t] = excl;
    foffs[2 * t + 1] = excl + a0;
    __syncthreads();
#pragma unroll
    for (int q = 0; q < 2; ++q) {
        int j = t + q * 256;
        int node = b * NPB + j;
        if (node < NN) offs[node] = rs + foffs[j];
    }
    for (int i = t; i < NPB; i += 256) fcnt[i] = 0;   // reuse as cursors
    __syncthreads();
    int i = t;
    for (; i + 768 < n; i += 1024) {
        unsigned int v0 = pkd[rs + i];
        unsigned int v1 = pkd[rs + i + 256];
        unsigned int v2 = pkd[rs + i + 512];
        unsigned int v3 = pkd[rs + i + 768];
        int j0 = v0 >> 17, j1 = v1 >> 17, j2 = v2 >> 17, j3 = v3 >> 17;
        int r0 = atomicAdd(&fcnt[j0], 1);
        int r1 = atomicAdd(&fcnt[j1], 1);
        int r2 = atomicAdd(&fcnt[j2], 1);
        int r3 = atomicAdd(&fcnt[j3], 1);
        csr_src[rs + foffs[j0] + r0] = (int)(v0 & 0x1FFFFu);
        csr_src[rs + foffs[j1] + r1] = (int)(v1 & 0x1FFFFu);
        csr_src[rs + foffs[j2] + r2] = (int)(v2 & 0x1FFFFu);
        csr_src[rs + foffs[j3] + r3] = (int)(v3 & 0x1FFFFu);
    }
    for (; i < n; i += 256) {
        unsigned int v = pkd[rs + i];
        int j = v >> 17;
        int r = atomicAdd(&fcnt[j], 1);
        csr_src[rs + foffs[j] + r] = (int)(v & 0x1FFFFu);
    }
}

// ---------------- softmax + aggregation (single pass) ----------------
// one wave = 4 nodes; 16 lanes per node; within-block degree sort (round 4).
// This round: concurrency-oriented gather.
//  - s_sv (pre-multiplied by 16) written BEFORE the el4/expf weight chain, and
//    round-0 gather loads issued before weights are computed -> expf chain
//    hides under gather latency.
//  - ping-pong double buffer (ua/ub, 8-deep each): round j+1's loads are in
//    flight while round j's FMAs run -> ~8 loads in flight continuously.
//  - packed f32 FMA (f32x2 -> v_pk_fma_f32): 4 pk-fma + 8 unpacks per uint4
//    instead of 8 fma + 8 unpacks.
#define CH 32
__global__ __launch_bounds__(256, 4) void aggregate_kernel(const uint4* __restrict__ featu4,
                                                           const float4* __restrict__ el4,
                                                           const float4* __restrict__ er4,
                                                           const int* __restrict__ offs,
                                                           const int* __restrict__ csr_src,
                                                           float* __restrict__ out) {
    __shared__ int    s_sv[4][4][CH + 1];
    __shared__ float4 s_a4[4][4][CH + 1];
    __shared__ int sdeg[16], smap[16];

    const int tid = threadIdx.x;
    const int lane = tid & 63, wv = tid >> 6;
    const int g = lane >> 4, sub = lane & 15;

    // within-block degree sort of the 16 nodes (O(16^2) rank compare)
    if (tid < 16) {
        int n0 = blockIdx.x * 16 + tid;            // NN == 6250*16 exactly
        sdeg[tid] = offs[n0 + 1] - offs[n0];
    }
    __syncthreads();
    if (tid < 16) {
        int d = sdeg[tid];
        int rank = 0;
#pragma unroll
        for (int j = 0; j < 16; ++j) {
            int dj = sdeg[j];
            rank += (dj < d) || (dj == d && j < tid);
        }
        smap[rank] = blockIdx.x * 16 + tid;
    }
    __syncthreads();
    const int node = smap[wv * 4 + g];
    const int beg = offs[node], end = offs[node + 1];

    const float4 erv = er4[node];
    float4 sm = make_float4(0.f, 0.f, 0.f, 0.f);
    f32x2 acc2[4];
#pragma unroll
    for (int i = 0; i < 4; ++i) acc2[i] = (f32x2){0.f, 0.f};

    for (int c0 = beg; c0 < end; c0 += CH) {
        int cnt = end - c0;
        if (cnt > CH) cnt = CH;

        // phase 1: indices -> LDS (pre-scaled by 16 for featu4 addressing)
        int svr[2];
#pragma unroll
        for (int t = 0; t < 2; ++t) {
            int slot = sub + t * 16;
            int sv = (slot < cnt) ? csr_src[c0 + slot] : 0;
            svr[t] = sv;
            s_sv[wv][g][slot] = sv * 16;
        }

        // phase 2: prologue — issue round-0 gather loads now
        uint4 ua[8], ub[8];
#pragma unroll
        for (int e = 0; e < 8; ++e)
            ua[e] = featu4[(size_t)s_sv[wv][g][e] + sub];

        // phase 3: weights (expf chain hides under the round-0 loads)
#pragma unroll
        for (int t = 0; t < 2; ++t) {
            int slot = sub + t * 16;
            float4 w = make_float4(0.f, 0.f, 0.f, 0.f);
            if (slot < cnt) {
                float4 e = el4[svr[t]];
                w.x = __expf(lrelu(e.x + erv.x));
                w.y = __expf(lrelu(e.y + erv.y));
                w.z = __expf(lrelu(e.z + erv.z));
                w.w = __expf(lrelu(e.w + erv.w));
                sm.x += w.x; sm.y += w.y; sm.z += w.z; sm.w += w.w;
            }
            s_a4[wv][g][slot] = w;
        }

        int rounds = (cnt + 7) >> 3;
        int jr = 0;
        while (true) {
            bool m1 = (jr + 1) < rounds;
            if (m1) {
                int nb = (jr + 1) << 3;
#pragma unroll
                for (int e = 0; e < 8; ++e)
                    ub[e] = featu4[(size_t)s_sv[wv][g][nb + e] + sub];
            }
            {
                int jb = jr << 3;
#pragma unroll
                for (int e = 0; e < 8; ++e) {
                    float4 we = s_a4[wv][g][jb + e];
                    uint4 u = ua[e];
                    f32x2 w0 = {we.x, we.x}, w1 = {we.y, we.y};
                    f32x2 w2 = {we.z, we.z}, w3 = {we.w, we.w};
                    acc2[0] = __builtin_elementwise_fma(w0, un2(u.x), acc2[0]);
                    acc2[1] = __builtin_elementwise_fma(w1, un2(u.y), acc2[1]);
                    acc2[2] = __builtin_elementwise_fma(w2, un2(u.z), acc2[2]);
                    acc2[3] = __builtin_elementwise_fma(w3, un2(u.w), acc2[3]);
                }
            }
            ++jr;
            if (!m1) break;
            bool m2 = (jr + 1) < rounds;
            if (m2) {
                int nb = (jr + 1) << 3;
#pragma unroll
                for (int e = 0; e < 8; ++e)
                    ua[e] = featu4[(size_t)s_sv[wv][g][nb + e] + sub];
            }
            {
                int jb = jr << 3;
#pragma unroll
                for (int e = 0; e < 8; ++e) {
                    float4 we = s_a4[wv][g][jb + e];
                    uint4 u = ub[e];
                    f32x2 w0 = {we.x, we.x}, w1 = {we.y, we.y};
                    f32x2 w2 = {we.z, we.z}, w3 = {we.w, we.w};
                    acc2[0] = __builtin_elementwise_fma(w0, un2(u.x), acc2[0]);
                    acc2[1] = __builtin_elementwise_fma(w1, un2(u.y), acc2[1]);
                    acc2[2] = __builtin_elementwise_fma(w2, un2(u.z), acc2[2]);
                    acc2[3] = __builtin_elementwise_fma(w3, un2(u.w), acc2[3]);
                }
            }
            ++jr;
            if (!m2) break;
        }
    }

    // reduce denominators across the 16 lanes of this node
#pragma unroll
    for (int o = 1; o < 16; o <<= 1) {
        sm.x += __shfl_xor(sm.x, o);
        sm.y += __shfl_xor(sm.y, o);
        sm.z += __shfl_xor(sm.z, o);
        sm.w += __shfl_xor(sm.w, o);
    }
    float ix = 1.f / fmaxf(sm.x, 1e-9f);
    float iy = 1.f / fmaxf(sm.y, 1e-9f);
    float iz = 1.f / fmaxf(sm.z, 1e-9f);
    float iw = 1.f / fmaxf(sm.w, 1e-9f);
    float ox = 0.25f * (acc2[0].x * ix + acc2[1].x * iy + acc2[2].x * iz + acc2[3].x * iw);
    float oy = 0.25f * (acc2[0].y * ix + acc2[1].y * iy + acc2[2].y * iz + acc2[3].y * iw);
    out[node * 32 + sub]      = ox;
    out[node * 32 + 16 + sub] = oy;
}

// ---------------- launch ----------------
extern "C" void kernel_launch(void* const* d_in, const int* in_sizes, int n_in,
                              void* d_out, int out_size, void* d_ws, size_t ws_size,
                              hipStream_t stream) {
    const float* x      = (const float*)d_in[0];
    const float* W      = (const float*)d_in[1];
    const float* attn_l = (const float*)d_in[2];
    const float* attn_r = (const float*)d_in[3];
    const int*   src    = (const int*)d_in[4];
    const int*   dst    = (const int*)d_in[5];
    float* out = (float*)d_out;

    char* p = (char*)d_ws;
    auto alloc = [&](size_t bytes) -> void* {
        void* r = (void*)p;
        p += (bytes + 255) & ~(size_t)255;
        return r;
    };
    unsigned short* featb = (unsigned short*)alloc((size_t)NN * HD * 2);
    unsigned int*   wswz  = (unsigned int*)alloc(4096 * 16);
    float* el      = (float*)alloc((size_t)NN * 4 * 4);
    float* er      = (float*)alloc((size_t)NN * 4 * 4);
    int*   offs    = (int*)alloc((size_t)(NN + 1) * 4);
    unsigned int* pkd = (unsigned int*)alloc((size_t)NE * 4);
    int*   csr     = (int*)alloc((size_t)NE * 4);
    int*   gbcnt   = (int*)alloc((size_t)NB1 * 4);
    int*   regstart= (int*)alloc((size_t)(NB1 + 1) * 4);
    int*   gcursor = (int*)alloc((size_t)NB1 * 4);

    hipMemsetAsync(gbcnt, 0, (size_t)NB1 * 4, stream);

    prep_w_kernel<<<16, 256, 0, stream>>>(W, wswz);
    gemm_kernel<<<(NN + 63) / 64, 256, 0, stream>>>(x, (const uint4*)wswz, attn_l, attn_r,
                                                    featb, el, er);
    precount_kernel<<<SC_BLOCKS, 256, 0, stream>>>((const int4*)dst, gbcnt);
    bscan_kernel<<<1, 256, 0, stream>>>(gbcnt, regstart, gcursor, offs);
    scatter_kernel<<<SC_BLOCKS, 256, 0, stream>>>((const int4*)src, (const int4*)dst,
                                                  gcursor, pkd);
    build_kernel<<<NB1, 256, 0, stream>>>(pkd, regstart, offs, csr);
    aggregate_kernel<<<NN / 16, 256, 0, stream>>>((const uint4*)featb, (const float4*)el,
                                                  (const float4*)er, offs, csr, out);
}

// Round 6
// 284.518 us; speedup vs baseline: 1.1232x; 1.0597x over previous
//
#include <hip/hip_runtime.h>
#include <math.h>

#define NN 100000
#define NE 1600000
#define IN_DIM 256
#define HD 128           // HEADS*OUT_DIM
#define NEG_SLOPE 0.2f

#define B1SH 9                         // 512 nodes per coarse bucket
#define NPB (1 << B1SH)                // 512
#define NB1 ((NN + NPB - 1) / NPB)     // 196 coarse buckets
#define SC_BLOCKS ((NE / 4 + 1023) / 1024)   // 391 blocks, 4096 edges each
#define GEMM_BLOCKS ((NN + 63) / 64)   // 1563

typedef __attribute__((ext_vector_type(8))) __bf16 bf16x8;
typedef __attribute__((ext_vector_type(4))) float floatx4;
typedef __attribute__((ext_vector_type(2))) float f32x2;

__device__ inline unsigned short f2bf(float f) {
    unsigned int b = __float_as_uint(f);
    b += 0x7fffu + ((b >> 16) & 1u);   // round-to-nearest-even
    return (unsigned short)(b >> 16);
}
__device__ inline unsigned int pk(float lo, float hi) {
    return (unsigned int)f2bf(lo) | ((unsigned int)f2bf(hi) << 16);
}
__device__ inline float lrelu(float v) { return (v > 0.f) ? v : v * NEG_SLOPE; }
__device__ inline f32x2 un2(unsigned int v) {
    f32x2 r;
    r.x = __uint_as_float(v << 16);
    r.y = __uint_as_float(v & 0xffff0000u);
    return r;
}

// ================= D1: precount (blocks 0..390)  ||  prep_w (391..406) ======
// precount writes its per-block histogram row non-atomically -> no memset
// of any buffer is needed anywhere in the pipeline.
__global__ __launch_bounds__(256) void d1_kernel(const float* __restrict__ W,
                                                 unsigned int* __restrict__ wswz,
                                                 const int4* __restrict__ dst4,
                                                 int* __restrict__ gcnt2d) {
    __shared__ int cnt[NB1];
    const int t = threadIdx.x;
    if (blockIdx.x < SC_BLOCKS) {
        // ---- precount role ----
        for (int i = t; i < NB1; i += 256) cnt[i] = 0;
        __syncthreads();
        int base4 = blockIdx.x * 1024;
#pragma unroll
        for (int k = 0; k < 4; ++k) {
            int gi = base4 + k * 256 + t;
            if (gi < NE / 4) {
                int4 d = dst4[gi];
                atomicAdd(&cnt[d.x >> B1SH], 1);
                atomicAdd(&cnt[d.y >> B1SH], 1);
                atomicAdd(&cnt[d.z >> B1SH], 1);
                atomicAdd(&cnt[d.w >> B1SH], 1);
            }
        }
        __syncthreads();
        for (int i = t; i < NB1; i += 256)
            gcnt2d[blockIdx.x * NB1 + i] = cnt[i];
    } else {
        // ---- prep_w role: swizzle W[256][128] fp32 -> bf16 B-fragments ----
        int g = (blockIdx.x - SC_BLOCKS) * 256 + t;   // 0..4095
        int lane = g & 63;
        int tt = (g >> 6) & 7;
        int c = g >> 9;
        int sub = lane & 15, quad = lane >> 4;
        int n = tt * 16 + sub;
        int kbase = c * 32 + quad * 8;
        unsigned int ob = (unsigned int)g * 4;
#pragma unroll
        for (int i = 0; i < 4; ++i) {
            float lo = W[(size_t)(kbase + 2 * i) * HD + n];
            float hi = W[(size_t)(kbase + 2 * i + 1) * HD + n];
            wswz[ob + i] = pk(lo, hi);
        }
    }
}

// ================= D2: scatter (blocks 0..390)  ||  gemm (391..) ===========
// scatter re-derives regstart + its block-prefix from gcnt2d (no global
// atomics, no bscan dispatch); block 0 publishes regstart for build.
// gemm is the round-1 MFMA kernel; scatter runs hidden under its shadow.
__global__ __launch_bounds__(256) void d2_kernel(const float* __restrict__ x,
                                                 const uint4* __restrict__ wswz,
                                                 const float* __restrict__ attn_l,
                                                 const float* __restrict__ attn_r,
                                                 unsigned short* __restrict__ featb,
                                                 float* __restrict__ el,
                                                 float* __restrict__ er,
                                                 const int4* __restrict__ src4,
                                                 const int4* __restrict__ dst4,
                                                 const int* __restrict__ gcnt2d,
                                                 unsigned int* __restrict__ pkd,
                                                 int* __restrict__ regstart) {
    __shared__ int cnt[NB1];
    __shared__ int gbase[NB1];
    __shared__ int sh[256];
    const int t = threadIdx.x;

    if (blockIdx.x < SC_BLOCKS) {
        // ---- scatter role ----
        const int b = blockIdx.x;
        // column sums + my block prefix over gcnt2d
        int colsum = 0, mypre = 0;
        if (t < NB1) {
            for (int bb = 0; bb < SC_BLOCKS; ++bb) {
                int v = gcnt2d[bb * NB1 + t];
                colsum += v;
                if (bb < b) mypre += v;
            }
        }
        sh[t] = (t < NB1) ? colsum : 0;
        __syncthreads();
        for (int o = 1; o < 256; o <<= 1) {
            int a = (t >= o) ? sh[t - o] : 0;
            __syncthreads();
            sh[t] += a;
            __syncthreads();
        }
        int rstart = sh[t] - ((t < NB1) ? colsum : 0);   // exclusive scan
        if (t < NB1) gbase[t] = rstart + mypre;
        if (b == 0 && t < NB1) regstart[t] = rstart;
        if (b == 0 && t == 0) regstart[NB1] = NE;
        for (int i = t; i < NB1; i += 256) cnt[i] = 0;
        __syncthreads();

        int base4 = b * 1024;
        unsigned int pkv[16];
        unsigned int brk[16];
#pragma unroll
        for (int k = 0; k < 4; ++k) {
            int gi = base4 + k * 256 + t;
            bool ok = gi < NE / 4;
            int gic = ok ? gi : 0;
            int4 s = src4[gic];
            int4 d = dst4[gic];
            int dd[4] = {d.x, d.y, d.z, d.w};
            int ss[4] = {s.x, s.y, s.z, s.w};
#pragma unroll
            for (int j4 = 0; j4 < 4; ++j4) {
                int e = k * 4 + j4;
                if (ok) {
                    int bk = dd[j4] >> B1SH;
                    int r = atomicAdd(&cnt[bk], 1);                      // local rank
                    brk[e] = ((unsigned int)bk << 12) | (unsigned int)r; // r < 4096
                    pkv[e] = ((unsigned int)(dd[j4] & (NPB - 1)) << 17) | (unsigned int)ss[j4];
                } else {
                    brk[e] = 0xFFFFFFFFu;
                }
            }
        }
        __syncthreads();
#pragma unroll
        for (int e = 0; e < 16; ++e) {
            if (brk[e] != 0xFFFFFFFFu) {
                int bk = brk[e] >> 12;
                int r = brk[e] & 0xFFF;
                pkd[gbase[bk] + r] = pkv[e];
            }
        }
    } else {
        // ---- gemm role (MFMA, no LDS) ----
        const int lane = t & 63, wv = t >> 6;
        const int sub = lane & 15, quad = lane >> 4;
        const int row0 = (blockIdx.x - SC_BLOCKS) * 64 + wv * 16;

        int m = row0 + sub;
        if (m >= NN) m = NN - 1;                 // clamp loads; stores guarded
        const float* xp = x + (size_t)m * IN_DIM + quad * 8;

        bf16x8 af[8];
#pragma unroll
        for (int h = 0; h < 2; ++h) {
            float4 raw[4][2];
#pragma unroll
            for (int c = 0; c < 4; ++c) {
                raw[c][0] = *(const float4*)(xp + (h * 4 + c) * 32);
                raw[c][1] = *(const float4*)(xp + (h * 4 + c) * 32 + 4);
            }
#pragma unroll
            for (int c = 0; c < 4; ++c) {
                uint4 au;
                au.x = pk(raw[c][0].x, raw[c][0].y);
                au.y = pk(raw[c][0].z, raw[c][0].w);
                au.z = pk(raw[c][1].x, raw[c][1].y);
                au.w = pk(raw[c][1].z, raw[c][1].w);
                af[h * 4 + c] = __builtin_bit_cast(bf16x8, au);
            }
        }

        floatx4 acc[8];
#pragma unroll
        for (int tt = 0; tt < 8; ++tt) acc[tt] = (floatx4){0.f, 0.f, 0.f, 0.f};

#pragma unroll
        for (int c = 0; c < 8; ++c) {
            uint4 bu[8];
#pragma unroll
            for (int tt = 0; tt < 8; ++tt) bu[tt] = wswz[(c * 8 + tt) * 64 + lane];
#pragma unroll
            for (int tt = 0; tt < 8; ++tt) {
                bf16x8 bfr = __builtin_bit_cast(bf16x8, bu[tt]);
                acc[tt] = __builtin_amdgcn_mfma_f32_16x16x32_bf16(af[c], bfr, acc[tt], 0, 0, 0);
            }
        }

        float al[8], ar[8];
#pragma unroll
        for (int tt = 0; tt < 8; ++tt) {
            al[tt] = attn_l[tt * 16 + sub];
            ar[tt] = attn_r[tt * 16 + sub];
        }

#pragma unroll
        for (int r = 0; r < 4; ++r) {
            int row = row0 + quad * 4 + r;       // C/D: row = quad*4 + reg
            uint4 fv;
            fv.x = pk(acc[0][r], acc[1][r]);
            fv.y = pk(acc[2][r], acc[3][r]);
            fv.z = pk(acc[4][r], acc[5][r]);
            fv.w = pk(acc[6][r], acc[7][r]);
            float pl[4], pr[4];
#pragma unroll
            for (int hh = 0; hh < 4; ++hh) {
                pl[hh] = acc[2 * hh][r] * al[2 * hh] + acc[2 * hh + 1][r] * al[2 * hh + 1];
                pr[hh] = acc[2 * hh][r] * ar[2 * hh] + acc[2 * hh + 1][r] * ar[2 * hh + 1];
            }
#pragma unroll
            for (int o = 1; o < 16; o <<= 1) {
#pragma unroll
                for (int hh = 0; hh < 4; ++hh) {
                    pl[hh] += __shfl_xor(pl[hh], o);
                    pr[hh] += __shfl_xor(pr[hh], o);
                }
            }
            if (row < NN) {
                *(uint4*)(featb + (size_t)row * HD + sub * 8) = fv;
                if (sub < 4) {
                    float vl = (sub == 0) ? pl[0] : (sub == 1) ? pl[1] : (sub == 2) ? pl[2] : pl[3];
                    float vr = (sub == 0) ? pr[0] : (sub == 1) ? pr[1] : (sub == 2) ? pr[2] : pr[3];
                    el[row * 4 + sub] = vl;
                    er[row * 4 + sub] = vr;
                }
            }
        }
    }
}

// ====== D3: build: fine histogram (= exact degrees), scan -> offs, place ====
__global__ __launch_bounds__(256) void build_kernel(const unsigned int* __restrict__ pkd,
                                                    const int* __restrict__ regstart,
                                                    int* __restrict__ offs,
                                                    int* __restrict__ csr_src) {
    __shared__ int fcnt[NPB];
    __shared__ int foffs[NPB];
    __shared__ int ssc[256];
    int b = blockIdx.x, t = threadIdx.x;
    int rs = regstart[b], re = regstart[b + 1];
    int n = re - rs;
    if (b == 0 && t == 0) offs[NN] = NE;

    for (int i = t; i < NPB; i += 256) fcnt[i] = 0;
    __syncthreads();
    for (int i = t; i < n; i += 256) {
        unsigned int v = pkd[rs + i];
        atomicAdd(&fcnt[v >> 17], 1);
    }
    __syncthreads();
    int a0 = fcnt[2 * t], a1 = fcnt[2 * t + 1];
    int s = a0 + a1;
    ssc[t] = s;
    __syncthreads();
    for (int o = 1; o < 256; o <<= 1) {
        int u = (t >= o) ? ssc[t - o] : 0;
        __syncthreads();
        ssc[t] += u;
        __syncthreads();
    }
    int excl = ssc[t] - s;
    foffs[2 * t] = excl;
    foffs[2 * t + 1] = excl + a0;
    __syncthreads();
#pragma unroll
    for (int q = 0; q < 2; ++q) {
        int j = t + q * 256;
        int node = b * NPB + j;
        if (node < NN) offs[node] = rs + foffs[j];
    }
    for (int i = t; i < NPB; i += 256) fcnt[i] = 0;   // reuse as cursors
    __syncthreads();
    int i = t;
    for (; i + 768 < n; i += 1024) {
        unsigned int v0 = pkd[rs + i];
        unsigned int v1 = pkd[rs + i + 256];
        unsigned int v2 = pkd[rs + i + 512];
        unsigned int v3 = pkd[rs + i + 768];
        int j0 = v0 >> 17, j1 = v1 >> 17, j2 = v2 >> 17, j3 = v3 >> 17;
        int r0 = atomicAdd(&fcnt[j0], 1);
        int r1 = atomicAdd(&fcnt[j1], 1);
        int r2 = atomicAdd(&fcnt[j2], 1);
        int r3 = atomicAdd(&fcnt[j3], 1);
        csr_src[rs + foffs[j0] + r0] = (int)(v0 & 0x1FFFFu);
        csr_src[rs + foffs[j1] + r1] = (int)(v1 & 0x1FFFFu);
        csr_src[rs + foffs[j2] + r2] = (int)(v2 & 0x1FFFFu);
        csr_src[rs + foffs[j3] + r3] = (int)(v3 & 0x1FFFFu);
    }
    for (; i < n; i += 256) {
        unsigned int v = pkd[rs + i];
        int j = v >> 17;
        int r = atomicAdd(&fcnt[j], 1);
        csr_src[rs + foffs[j] + r] = (int)(v & 0x1FFFFu);
    }
}

// ====== D4: softmax + aggregation (round-5 version, at fabric ceiling) ======
#define CH 32
__global__ __launch_bounds__(256, 4) void aggregate_kernel(const uint4* __restrict__ featu4,
                                                           const float4* __restrict__ el4,
                                                           const float4* __restrict__ er4,
                                                           const int* __restrict__ offs,
                                                           const int* __restrict__ csr_src,
                                                           float* __restrict__ out) {
    __shared__ int    s_sv[4][4][CH + 1];
    __shared__ float4 s_a4[4][4][CH + 1];
    __shared__ int sdeg[16], smap[16];

    const int tid = threadIdx.x;
    const int lane = tid & 63, wv = tid >> 6;
    const int g = lane >> 4, sub = lane & 15;

    // within-block degree sort of the 16 nodes (O(16^2) rank compare)
    if (tid < 16) {
        int n0 = blockIdx.x * 16 + tid;            // NN == 6250*16 exactly
        sdeg[tid] = offs[n0 + 1] - offs[n0];
    }
    __syncthreads();
    if (tid < 16) {
        int d = sdeg[tid];
        int rank = 0;
#pragma unroll
        for (int j = 0; j < 16; ++j) {
            int dj = sdeg[j];
            rank += (dj < d) || (dj == d && j < tid);
        }
        smap[rank] = blockIdx.x * 16 + tid;
    }
    __syncthreads();
    const int node = smap[wv * 4 + g];
    const int beg = offs[node], end = offs[node + 1];

    const float4 erv = er4[node];
    float4 sm = make_float4(0.f, 0.f, 0.f, 0.f);
    f32x2 acc2[4];
#pragma unroll
    for (int i = 0; i < 4; ++i) acc2[i] = (f32x2){0.f, 0.f};

    for (int c0 = beg; c0 < end; c0 += CH) {
        int cnt = end - c0;
        if (cnt > CH) cnt = CH;

        // phase 1: indices -> LDS (pre-scaled by 16 for featu4 addressing)
        int svr[2];
#pragma unroll
        for (int t = 0; t < 2; ++t) {
            int slot = sub + t * 16;
            int sv = (slot < cnt) ? csr_src[c0 + slot] : 0;
            svr[t] = sv;
            s_sv[wv][g][slot] = sv * 16;
        }

        // phase 2: prologue — issue round-0 gather loads now
        uint4 ua[8], ub[8];
#pragma unroll
        for (int e = 0; e < 8; ++e)
            ua[e] = featu4[(size_t)s_sv[wv][g][e] + sub];

        // phase 3: weights (expf chain hides under the round-0 loads)
#pragma unroll
        for (int t = 0; t < 2; ++t) {
            int slot = sub + t * 16;
            float4 w = make_float4(0.f, 0.f, 0.f, 0.f);
            if (slot < cnt) {
                float4 e = el4[svr[t]];
                w.x = __expf(lrelu(e.x + erv.x));
                w.y = __expf(lrelu(e.y + erv.y));
                w.z = __expf(lrelu(e.z + erv.z));
                w.w = __expf(lrelu(e.w + erv.w));
                sm.x += w.x; sm.y += w.y; sm.z += w.z; sm.w += w.w;
            }
            s_a4[wv][g][slot] = w;
        }

        int rounds = (cnt + 7) >> 3;
        int jr = 0;
        while (true) {
            bool m1 = (jr + 1) < rounds;
            if (m1) {
                int nb = (jr + 1) << 3;
#pragma unroll
                for (int e = 0; e < 8; ++e)
                    ub[e] = featu4[(size_t)s_sv[wv][g][nb + e] + sub];
            }
            {
                int jb = jr << 3;
#pragma unroll
                for (int e = 0; e < 8; ++e) {
                    float4 we = s_a4[wv][g][jb + e];
                    uint4 u = ua[e];
                    f32x2 w0 = {we.x, we.x}, w1 = {we.y, we.y};
                    f32x2 w2 = {we.z, we.z}, w3 = {we.w, we.w};
                    acc2[0] = __builtin_elementwise_fma(w0, un2(u.x), acc2[0]);
                    acc2[1] = __builtin_elementwise_fma(w1, un2(u.y), acc2[1]);
                    acc2[2] = __builtin_elementwise_fma(w2, un2(u.z), acc2[2]);
                    acc2[3] = __builtin_elementwise_fma(w3, un2(u.w), acc2[3]);
                }
            }
            ++jr;
            if (!m1) break;
            bool m2 = (jr + 1) < rounds;
            if (m2) {
                int nb = (jr + 1) << 3;
#pragma unroll
                for (int e = 0; e < 8; ++e)
                    ua[e] = featu4[(size_t)s_sv[wv][g][nb + e] + sub];
            }
            {
                int jb = jr << 3;
#pragma unroll
                for (int e = 0; e < 8; ++e) {
                    float4 we = s_a4[wv][g][jb + e];
                    uint4 u = ub[e];
                    f32x2 w0 = {we.x, we.x}, w1 = {we.y, we.y};
                    f32x2 w2 = {we.z, we.z}, w3 = {we.w, we.w};
                    acc2[0] = __builtin_elementwise_fma(w0, un2(u.x), acc2[0]);
                    acc2[1] = __builtin_elementwise_fma(w1, un2(u.y), acc2[1]);
                    acc2[2] = __builtin_elementwise_fma(w2, un2(u.z), acc2[2]);
                    acc2[3] = __builtin_elementwise_fma(w3, un2(u.w), acc2[3]);
                }
            }
            ++jr;
            if (!m2) break;
        }
    }

    // reduce denominators across the 16 lanes of this node
#pragma unroll
    for (int o = 1; o < 16; o <<= 1) {
        sm.x += __shfl_xor(sm.x, o);
        sm.y += __shfl_xor(sm.y, o);
        sm.z += __shfl_xor(sm.z, o);
        sm.w += __shfl_xor(sm.w, o);
    }
    float ix = 1.f / fmaxf(sm.x, 1e-9f);
    float iy = 1.f / fmaxf(sm.y, 1e-9f);
    float iz = 1.f / fmaxf(sm.z, 1e-9f);
    float iw = 1.f / fmaxf(sm.w, 1e-9f);
    float ox = 0.25f * (acc2[0].x * ix + acc2[1].x * iy + acc2[2].x * iz + acc2[3].x * iw);
    float oy = 0.25f * (acc2[0].y * ix + acc2[1].y * iy + acc2[2].y * iz + acc2[3].y * iw);
    out[node * 32 + sub]      = ox;
    out[node * 32 + 16 + sub] = oy;
}

// ---------------- launch ----------------
extern "C" void kernel_launch(void* const* d_in, const int* in_sizes, int n_in,
                              void* d_out, int out_size, void* d_ws, size_t ws_size,
                              hipStream_t stream) {
    const float* x      = (const float*)d_in[0];
    const float* W      = (const float*)d_in[1];
    const float* attn_l = (const float*)d_in[2];
    const float* attn_r = (const float*)d_in[3];
    const int*   src    = (const int*)d_in[4];
    const int*   dst    = (const int*)d_in[5];
    float* out = (float*)d_out;

    char* p = (char*)d_ws;
    auto alloc = [&](size_t bytes) -> void* {
        void* r = (void*)p;
        p += (bytes + 255) & ~(size_t)255;
        return r;
    };
    unsigned short* featb = (unsigned short*)alloc((size_t)NN * HD * 2);
    unsigned int*   wswz  = (unsigned int*)alloc(4096 * 16);
    float* el      = (float*)alloc((size_t)NN * 4 * 4);
    float* er      = (float*)alloc((size_t)NN * 4 * 4);
    int*   offs    = (int*)alloc((size_t)(NN + 1) * 4);
    unsigned int* pkd = (unsigned int*)alloc((size_t)NE * 4);
    int*   csr     = (int*)alloc((size_t)NE * 4);
    int*   gcnt2d  = (int*)alloc((size_t)SC_BLOCKS * NB1 * 4);
    int*   regstart= (int*)alloc((size_t)(NB1 + 1) * 4);

    d1_kernel<<<SC_BLOCKS + 16, 256, 0, stream>>>(W, wswz, (const int4*)dst, gcnt2d);
    d2_kernel<<<SC_BLOCKS + GEMM_BLOCKS, 256, 0, stream>>>(x, (const uint4*)wswz, attn_l, attn_r,
                                                           featb, el, er,
                                                           (const int4*)src, (const int4*)dst,
                                                           gcnt2d, pkd, regstart);
    build_kernel<<<NB1, 256, 0, stream>>>(pkd, regstart, offs, csr);
    aggregate_kernel<<<NN / 16, 256, 0, stream>>>((const uint4*)featb, (const float4*)el,
                                                  (const float4*)er, offs, csr, out);
}